// Round 25
// baseline (32.407 us; speedup 1.0000x reference)
//
#include <hip/hip_runtime.h>

// GaussianAntecedent: out[n,r] = mem[n,r] / (sum_r mem[n,r] + 1e-8)
// mem = exp2( -sum_d clamp(q*x+pn, +-K)^2 ),  K = sqrt(-log2(1e-8))
//   q = sqrt(0.5*log2 e)/(sigma+eps), pn = -c*q
//
// R24 post-mortem: v_pk_max/min_f32 don't exist on gfx950 -- packed
// clamp dead. Floor re-derivation: R23's 256 uniform ds_read_b128/wave
// serve 2048 (row,rule) cells = 1.5cy/cell of LDS-pipe service =
// ~15.6us/CU -- the binding roof (VALU only ~8us). R25: FOUR rows per
// lane (ROWS=256/block): same 256 reads serve 4096 cells -> 0.75cy/cell,
// LDS floor ~8us. mem stays in REGISTERS (4x16, static indexing, fully
// unrolled), direct float4 stores (R15: ~+1us only), no memL at all.
// LDS = tabL 16KB + partL 5KB + rsL 1KB = 22KB; VGPR ~240 (256,2).

typedef float v2f __attribute__((ext_vector_type(2)));

constexpr int DDIM = 32;
constexpr int RR   = 64;
constexpr int ROWS = 256;   // rows per block (4 per lane)
constexpr int PP   = 5;     // partials pitch (floats)

__device__ inline float fast_exp2(float x) {
#if __has_builtin(__builtin_amdgcn_exp2f)
    return __builtin_amdgcn_exp2f(x);
#else
    return exp2f(x);
#endif
}

__global__ __launch_bounds__(256, 2) void gauss_main(
    const float* __restrict__ X,
    const float* __restrict__ centers,
    const float* __restrict__ sigma,
    float* __restrict__ out, int N)
{
    __shared__ float tabL[RR * 64];       // 16 KB  [rule]{q[32]|pn[32]}
    __shared__ float partL[ROWS * PP];    // 5.1 KB [row][wave]
    __shared__ float rsL[ROWS];           // 1 KB   rcp(S) per row

    const int tid  = threadIdx.x;
    const int lane = tid & 63;
    const int w    = tid >> 6;
    const int n0   = blockIdx.x * ROWS;

    // ---- own 4 rows -> VGPRs (issued first; hides table build) ----
    int nr[4], cr_[4];
    #pragma unroll
    for (int s = 0; s < 4; ++s) {
        nr[s] = n0 + s * 64 + lane;
        cr_[s] = (nr[s] < N) ? nr[s] : (N - 1);
    }
    v2f x2[4][16];
    #pragma unroll
    for (int s = 0; s < 4; ++s) {
        const float4* __restrict__ xr =
            reinterpret_cast<const float4*>(X + (size_t)cr_[s] * DDIM);
        #pragma unroll
        for (int j = 0; j < 8; ++j) {
            float4 v = xr[j];
            x2[s][2 * j]     = (v2f){v.x, v.y};
            x2[s][2 * j + 1] = (v2f){v.z, v.w};
        }
    }

    // ---- build q/pn table in LDS (once per block; 8 divides/thread) ----
    const float SQK = 0.84932180028801907f;   // sqrt(0.5 * log2(e))
    #pragma unroll
    for (int i = 0; i < 8; ++i) {
        const int pi = tid * 8 + i;           // (rule, dim) pair 0..2047
        const int r  = pi >> 5, d = pi & 31;
        float q  = SQK / (sigma[r * DDIM + d] + 1e-8f);
        tabL[r * 64 + d]        = q;
        tabL[r * 64 + DDIM + d] = -centers[r * DDIM + d] * q;
    }

    __syncthreads();   // table ready

    const float K = 5.1551357f;   // sqrt(26.575424759098897) = sqrt(-log2 1e-8)
    float mem_[4][16];            // static indexing only (fully unrolled)
    float S[4] = {0.f, 0.f, 0.f, 0.f};

    // ---- 16 rules for this wave; each constant read feeds 4 rows ----
    #pragma unroll
    for (int rr = 0; rr < 16; ++rr) {
        const int r = w * 16 + rr;
        const float4* __restrict__ tp =
            reinterpret_cast<const float4*>(&tabL[r * 64]);

        v2f A[4][2] = {{{0.f,0.f},{0.f,0.f}}, {{0.f,0.f},{0.f,0.f}},
                       {{0.f,0.f},{0.f,0.f}}, {{0.f,0.f},{0.f,0.f}}};
        #pragma unroll
        for (int j = 0; j < 8; ++j) {
            float4 qf = tp[j];        // q  dims 4j..4j+3 (uniform broadcast)
            float4 pf = tp[8 + j];    // pn dims 4j..4j+3
            v2f q0 = {qf.x, qf.y}, q1 = {qf.z, qf.w};
            v2f p0 = {pf.x, pf.y}, p1 = {pf.z, pf.w};
            #pragma unroll
            for (int s = 0; s < 4; ++s) {
                v2f t0 = __builtin_elementwise_fma(q0, x2[s][2*j],   p0);
                v2f t1 = __builtin_elementwise_fma(q1, x2[s][2*j+1], p1);
                // clamp to [-K, K]: fminf(fmaxf(.)) fuses to v_med3_f32
                t0.x = fminf(fmaxf(t0.x, -K), K); t0.y = fminf(fmaxf(t0.y, -K), K);
                t1.x = fminf(fmaxf(t1.x, -K), K); t1.y = fminf(fmaxf(t1.y, -K), K);
                A[s][0] = __builtin_elementwise_fma(t0, -t0, A[s][0]);
                A[s][1] = __builtin_elementwise_fma(t1, -t1, A[s][1]);
            }
        }
        #pragma unroll
        for (int s = 0; s < 4; ++s) {
            v2f a = A[s][0] + A[s][1];
            float m = fast_exp2(a.x + a.y);
            mem_[s][rr] = m;
            S[s] += m;
        }
    }
    #pragma unroll
    for (int s = 0; s < 4; ++s)
        partL[(s * 64 + lane) * PP + w] = S[s];   // (5*row+w)%32: 2-way, free

    __syncthreads();   // partials ready

    // every thread owns one row's rcp(S): tid = row 0..255
    {
        float s = partL[tid * PP + 0] + partL[tid * PP + 1] +
                  partL[tid * PP + 2] + partL[tid * PP + 3];
        rsL[tid] = __builtin_amdgcn_rcpf(s + 1e-8f);
    }
    __syncthreads();   // rs ready

    // ---- direct stores: lane owns 64B (16 rules) of each of its 4 rows ----
    #pragma unroll
    for (int s = 0; s < 4; ++s) {
        if (nr[s] < N) {
            float rs = rsL[s * 64 + lane];
            float* op = out + (size_t)nr[s] * RR + w * 16;
            #pragma unroll
            for (int q = 0; q < 4; ++q) {
                float4 o;
                o.x = mem_[s][4*q+0] * rs; o.y = mem_[s][4*q+1] * rs;
                o.z = mem_[s][4*q+2] * rs; o.w = mem_[s][4*q+3] * rs;
                *reinterpret_cast<float4*>(op + 4 * q) = o;
            }
        }
    }
}

extern "C" void kernel_launch(void* const* d_in, const int* in_sizes, int n_in,
                              void* d_out, int out_size, void* d_ws, size_t ws_size,
                              hipStream_t stream) {
    const float* X       = (const float*)d_in[0];
    const float* centers = (const float*)d_in[1];
    const float* sigma   = (const float*)d_in[2];
    float* out = (float*)d_out;

    const int N = in_sizes[0] / DDIM;  // 100000
    const int grid = (N + ROWS - 1) / ROWS;   // 391 (last block: 160 rows)
    gauss_main<<<grid, 256, 0, stream>>>(X, centers, sigma, out, N);
}